// Round 7
// baseline (590.727 us; speedup 1.0000x reference)
//
#include <hip/hip_runtime.h>

#define T_CTX 2048
#define C_DIM 1024
#define HQK   256
#define NVOC  50257

typedef float nfloat4 __attribute__((ext_vector_type(4)));

// ---------------------------------------------------------------------------
// Kernel 1 (single block, 1024 thr): clears vocab_map AND builds
// first-occurrence map via an LDS hash table (atomicCAS claim + atomicMin pos).
// ---------------------------------------------------------------------------
__global__ __launch_bounds__(1024) void k_build_first(const int* __restrict__ idx,
                                                      int* __restrict__ first,
                                                      int* __restrict__ vocab_map) {
    __shared__ int sidx[T_CTX];
    __shared__ int skey[4096];
    __shared__ int sval[4096];
    const int tid = threadIdx.x;
    for (int i = tid; i < T_CTX; i += 1024) sidx[i] = idx[i];
    for (int i = tid; i < 4096; i += 1024) { skey[i] = -1; sval[i] = 0x7fffffff; }
    int4* vm4 = reinterpret_cast<int4*>(vocab_map);
    const int4 neg1 = make_int4(-1, -1, -1, -1);
    for (int i = tid; i < 12564; i += 1024) vm4[i] = neg1;
    if (tid == 0) vocab_map[NVOC - 1] = -1;
    __syncthreads();
#pragma unroll
    for (int rep = 0; rep < 2; ++rep) {
        const int s = tid + rep * 1024;
        const int my = sidx[s];
        int h = (int)(((unsigned)my * 2654435761u) >> 16) & 4095;
        while (true) {
            int k = skey[h];
            if (k == my) break;
            if (k == -1) {
                int old = atomicCAS(&skey[h], -1, my);
                if (old == -1 || old == my) break;
            }
            h = (h + 1) & 4095;
        }
        atomicMin(&sval[h], s);
    }
    __syncthreads();
#pragma unroll
    for (int rep = 0; rep < 2; ++rep) {
        const int s = tid + rep * 1024;
        const int my = sidx[s];
        int h = (int)(((unsigned)my * 2654435761u) >> 16) & 4095;
        while (skey[h] != my) h = (h + 1) & 4095;
        const int mp = sval[h];
        first[s] = mp;
        if (mp == s) vocab_map[my] = s;
    }
}

// ---------------------------------------------------------------------------
// Kernel 2: fused q/k projection.  128x64 tile, BK=32, 512 threads (8 waves),
// 4x4 micro via 2x ds_read_b128 per kk (16 FMA : 24 LDS-cyc -> VALU-bound).
// cols 0..255 -> qbuf [T][256]; cols 256..511 -> kT [256][T] (transposed).
// ---------------------------------------------------------------------------
__global__ __launch_bounds__(512) void k_gemm_qk(const float* __restrict__ x,
                                                 const float* __restrict__ Wq,
                                                 const float* __restrict__ Wk,
                                                 float* __restrict__ qbuf,
                                                 float* __restrict__ kT) {
    __shared__ __align__(16) float As[32 * 132];   // [kk][row], rows 0..127
    __shared__ __align__(16) float Bs[32 * 68];    // [kk][col]
    const int row0 = blockIdx.x * 128;
    const int col0 = blockIdx.y * 64;
    const bool is_q = (col0 < HQK);
    const float* __restrict__ W = is_q ? Wq : Wk;
    const int wc0 = is_q ? col0 : (col0 - HQK);
    const int tid = threadIdx.x;
    const int tr = (tid >> 4) << 2;     // 0..124
    const int tc = (tid & 15) << 2;     // 0..60
    const int ak = (tid & 7) << 2;      // A: k-quad offset
    const int ar0 = tid >> 3;           // A: row (0..63), +64 for L=1
    const int bk = tid >> 4, bc = (tid & 15) << 2;   // B: 32 k x 16 quads
    float acc[4][4] = {};
    for (int k0 = 0; k0 < C_DIM; k0 += 32) {
#pragma unroll
        for (int L = 0; L < 2; ++L) {
            const int ar = ar0 + (L << 6);
            float4 a4 = *reinterpret_cast<const float4*>(&x[(size_t)(row0 + ar) * C_DIM + k0 + ak]);
            As[(ak + 0) * 132 + ar] = a4.x; As[(ak + 1) * 132 + ar] = a4.y;
            As[(ak + 2) * 132 + ar] = a4.z; As[(ak + 3) * 132 + ar] = a4.w;
        }
        float4 b4 = *reinterpret_cast<const float4*>(&W[(size_t)(k0 + bk) * HQK + wc0 + bc]);
        *reinterpret_cast<float4*>(&Bs[bk * 68 + bc]) = b4;
        __syncthreads();
#pragma unroll
        for (int kk = 0; kk < 32; ++kk) {
            float4 av = *reinterpret_cast<const float4*>(&As[kk * 132 + tr]);
            float4 bv = *reinterpret_cast<const float4*>(&Bs[kk * 68 + tc]);
            const float a[4] = {av.x, av.y, av.z, av.w};
            const float b[4] = {bv.x, bv.y, bv.z, bv.w};
#pragma unroll
            for (int i = 0; i < 4; ++i)
#pragma unroll
                for (int j = 0; j < 4; ++j) acc[i][j] = fmaf(a[i], b[j], acc[i][j]);
        }
        __syncthreads();
    }
    if (is_q) {
#pragma unroll
        for (int i = 0; i < 4; ++i) {
            float4 o = {acc[i][0], acc[i][1], acc[i][2], acc[i][3]};
            *reinterpret_cast<float4*>(&qbuf[(size_t)(row0 + tr + i) * HQK + col0 + tc]) = o;
        }
    } else {
#pragma unroll
        for (int j = 0; j < 4; ++j) {
            float4 o = {acc[0][j], acc[1][j], acc[2][j], acc[3][j]};
            *reinterpret_cast<float4*>(&kT[(size_t)(wc0 + tc + j) * T_CTX + row0 + tr]) = o;
        }
    }
}

// ---------------------------------------------------------------------------
// Kernel 3: causal score GEMM.  c[t][s] = q[t].k[s] / 256.  128x64 tile,
// BK=32, 512 threads, 4x4 micro; K=256 -> 8 stages.  Grid (16,32); blocks
// with bs > 2*bt+1 (fully above diagonal) exit.  Diagonal-crossing garbage
// is masked element-wise by the fold (quads never extend past (t|3), which
// stays inside written blocks).
// ---------------------------------------------------------------------------
__global__ __launch_bounds__(512) void k_scores_gemm(const float* __restrict__ q,
                                                     const float* __restrict__ kT,
                                                     float* __restrict__ c) {
    const int bt = blockIdx.x, bs = blockIdx.y;
    if (bs > 2 * bt + 1) return;
    __shared__ __align__(16) float As[32 * 132];
    __shared__ __align__(16) float Bs[32 * 68];
    const int row0 = bt * 128;   // t
    const int col0 = bs * 64;    // s
    const int tid = threadIdx.x;
    const int tr = (tid >> 4) << 2;
    const int tc = (tid & 15) << 2;
    const int ak = (tid & 7) << 2;
    const int ar0 = tid >> 3;
    const int bk = tid >> 4, bc = (tid & 15) << 2;
    float acc[4][4] = {};
    for (int k0 = 0; k0 < HQK; k0 += 32) {
#pragma unroll
        for (int L = 0; L < 2; ++L) {
            const int ar = ar0 + (L << 6);
            float4 a4 = *reinterpret_cast<const float4*>(&q[(size_t)(row0 + ar) * HQK + k0 + ak]);
            As[(ak + 0) * 132 + ar] = a4.x; As[(ak + 1) * 132 + ar] = a4.y;
            As[(ak + 2) * 132 + ar] = a4.z; As[(ak + 3) * 132 + ar] = a4.w;
        }
        float4 b4 = *reinterpret_cast<const float4*>(&kT[(size_t)(k0 + bk) * T_CTX + col0 + bc]);
        *reinterpret_cast<float4*>(&Bs[bk * 68 + bc]) = b4;
        __syncthreads();
#pragma unroll
        for (int kk = 0; kk < 32; ++kk) {
            float4 av = *reinterpret_cast<const float4*>(&As[kk * 132 + tr]);
            float4 bv = *reinterpret_cast<const float4*>(&Bs[kk * 68 + tc]);
            const float a[4] = {av.x, av.y, av.z, av.w};
            const float b[4] = {bv.x, bv.y, bv.z, bv.w};
#pragma unroll
            for (int i = 0; i < 4; ++i)
#pragma unroll
                for (int j = 0; j < 4; ++j) acc[i][j] = fmaf(a[i], b[j], acc[i][j]);
        }
        __syncthreads();
    }
    const float scale = 1.0f / 256.0f;
#pragma unroll
    for (int i = 0; i < 4; ++i) {
        float4 o = {acc[i][0] * scale, acc[i][1] * scale, acc[i][2] * scale, acc[i][3] * scale};
        *reinterpret_cast<float4*>(&c[(size_t)(row0 + tr + i) * T_CTX + col0 + tc]) = o;
    }
}

// ---------------------------------------------------------------------------
// Kernel 4 (fused fold+expand): block t
//   phase A: fold row t of c by first[] into LDS rowc[2048] (LDS atomics)
//   phase B: stream-expand rowc to out[t][0..VOCAB) with aligned nontemporal
//            float4 stores (per-row lead fixup since NVOC%4==1).
// ---------------------------------------------------------------------------
__global__ __launch_bounds__(256) void k_fold_expand(const float* __restrict__ c,
                                                     const int* __restrict__ first,
                                                     const int* __restrict__ vocab_map,
                                                     float* __restrict__ out) {
    __shared__ float rowc[T_CTX];
    const int t = blockIdx.x;
    for (int i = threadIdx.x; i < T_CTX; i += 256) rowc[i] = 0.0f;
    __syncthreads();
    const int nq = (t >> 2) + 1;
    for (int qd = threadIdx.x; qd < nq; qd += 256) {
        const int s0 = qd << 2;
        float4 v = *reinterpret_cast<const float4*>(&c[(size_t)t * T_CTX + s0]);
        int4 f4 = *reinterpret_cast<const int4*>(&first[s0]);
        if (s0 + 3 <= t) {
            atomicAdd(&rowc[f4.x], v.x); atomicAdd(&rowc[f4.y], v.y);
            atomicAdd(&rowc[f4.z], v.z); atomicAdd(&rowc[f4.w], v.w);
        } else {
            atomicAdd(&rowc[f4.x], v.x);
            if (s0 + 1 <= t) atomicAdd(&rowc[f4.y], v.y);
            if (s0 + 2 <= t) atomicAdd(&rowc[f4.z], v.z);
            if (s0 + 3 <= t) atomicAdd(&rowc[f4.w], v.w);
        }
    }
    __syncthreads();
    float* __restrict__ orow = out + (size_t)t * NVOC;
    const int lead = (4 - (t & 3)) & 3;
    if ((int)threadIdx.x < lead) {
        int m = vocab_map[threadIdx.x];
        orow[threadIdx.x] = (m >= 0) ? rowc[m] : 0.0f;
    }
    const int nvec = (NVOC - lead) >> 2;
    for (int i = threadIdx.x; i < nvec; i += 256) {
        const int v = lead + (i << 2);
        int m0 = vocab_map[v + 0], m1 = vocab_map[v + 1];
        int m2 = vocab_map[v + 2], m3 = vocab_map[v + 3];
        nfloat4 o;
        o.x = (m0 >= 0) ? rowc[m0] : 0.0f;
        o.y = (m1 >= 0) ? rowc[m1] : 0.0f;
        o.z = (m2 >= 0) ? rowc[m2] : 0.0f;
        o.w = (m3 >= 0) ? rowc[m3] : 0.0f;
        __builtin_nontemporal_store(o, reinterpret_cast<nfloat4*>(&orow[v]));
    }
    for (int v = lead + (nvec << 2) + threadIdx.x; v < NVOC; v += 256) {
        int m = vocab_map[v];
        orow[v] = (m >= 0) ? rowc[m] : 0.0f;
    }
}

// ---------------------------------------------------------------------------
extern "C" void kernel_launch(void* const* d_in, const int* in_sizes, int n_in,
                              void* d_out, int out_size, void* d_ws, size_t ws_size,
                              hipStream_t stream) {
    const float* x   = (const float*)d_in[0];
    const int*   idx = (const int*)d_in[1];
    const float* Wq  = (const float*)d_in[2];
    const float* Wk  = (const float*)d_in[3];
    float* out = (float*)d_out;

    char* ws = (char*)d_ws;
    float* qbuf      = (float*)(ws);                              // 2 MB  [T][256]
    float* kT        = (float*)(ws + (2u << 20));                 // 2 MB  [256][T]
    float* c         = (float*)(ws + (4u << 20));                 // 16 MB [T][T] raw scores
    int*   first     = (int*)(ws + (20u << 20));                  // 8 KB
    int*   vocab_map = (int*)(ws + (20u << 20) + (16u << 10));    // ~200 KB

    k_build_first<<<1, 1024, 0, stream>>>(idx, first, vocab_map);
    dim3 gg(16, 8);
    k_gemm_qk<<<gg, 512, 0, stream>>>(x, Wq, Wk, qbuf, kT);
    dim3 gs(16, 32);
    k_scores_gemm<<<gs, 512, 0, stream>>>(qbuf, kT, c);
    k_fold_expand<<<T_CTX, 256, 0, stream>>>(c, first, vocab_map, out);
}

// Round 10
// 588.816 us; speedup vs baseline: 1.0032x; 1.0032x over previous
//
#include <hip/hip_runtime.h>

#define T_CTX 2048
#define C_DIM 1024
#define HQK   256
#define NVOC  50257

typedef float nfloat4 __attribute__((ext_vector_type(4)));

// ---------------------------------------------------------------------------
// Kernel 1 (single block, 1024 thr): clears vocab_map, builds first-occurrence
// map via LDS hash table, and emits the duplicate list (s with first[s]!=s).
// ---------------------------------------------------------------------------
__global__ __launch_bounds__(1024) void k_build_first(const int* __restrict__ idx,
                                                      int* __restrict__ first,
                                                      int* __restrict__ vocab_map,
                                                      int* __restrict__ ndup_g,
                                                      int* __restrict__ dup_s,
                                                      int* __restrict__ dup_f) {
    __shared__ int sidx[T_CTX];
    __shared__ int skey[4096];
    __shared__ int sval[4096];
    __shared__ int sndup;
    const int tid = threadIdx.x;
    for (int i = tid; i < T_CTX; i += 1024) sidx[i] = idx[i];
    for (int i = tid; i < 4096; i += 1024) { skey[i] = -1; sval[i] = 0x7fffffff; }
    int4* vm4 = reinterpret_cast<int4*>(vocab_map);
    const int4 neg1 = make_int4(-1, -1, -1, -1);
    for (int i = tid; i < 12564; i += 1024) vm4[i] = neg1;
    if (tid == 0) { vocab_map[NVOC - 1] = -1; sndup = 0; }
    __syncthreads();
#pragma unroll
    for (int rep = 0; rep < 2; ++rep) {
        const int s = tid + rep * 1024;
        const int my = sidx[s];
        int h = (int)(((unsigned)my * 2654435761u) >> 16) & 4095;
        while (true) {
            int k = skey[h];
            if (k == my) break;
            if (k == -1) {
                int old = atomicCAS(&skey[h], -1, my);
                if (old == -1 || old == my) break;
            }
            h = (h + 1) & 4095;
        }
        atomicMin(&sval[h], s);
    }
    __syncthreads();
#pragma unroll
    for (int rep = 0; rep < 2; ++rep) {
        const int s = tid + rep * 1024;
        const int my = sidx[s];
        int h = (int)(((unsigned)my * 2654435761u) >> 16) & 4095;
        while (skey[h] != my) h = (h + 1) & 4095;
        const int mp = sval[h];
        first[s] = mp;
        if (mp == s) {
            vocab_map[my] = s;
        } else {
            int p = atomicAdd(&sndup, 1);
            dup_s[p] = s; dup_f[p] = mp;
        }
    }
    __syncthreads();
    if (tid == 0) ndup_g[0] = sndup;
}

// ---------------------------------------------------------------------------
// Kernel 2: fused q/k projection (R6 structure: 64x64 tile, BK=32, 512 thr,
// 2x4 micro).  q -> qbuf [T][256]; k -> kT [256][T] AND kbuf [T][256]
// (row-major copy used by the rare correction path).
// ---------------------------------------------------------------------------
__global__ __launch_bounds__(512) void k_gemm_qk(const float* __restrict__ x,
                                                 const float* __restrict__ Wq,
                                                 const float* __restrict__ Wk,
                                                 float* __restrict__ qbuf,
                                                 float* __restrict__ kT,
                                                 float* __restrict__ kbuf) {
    __shared__ __align__(16) float As[32 * 68];
    __shared__ __align__(16) float Bs[32 * 68];
    const int row0 = blockIdx.x * 64;
    const int col0 = blockIdx.y * 64;
    const bool is_q = (col0 < HQK);
    const float* __restrict__ W = is_q ? Wq : Wk;
    const int wc0 = is_q ? col0 : (col0 - HQK);
    const int tid = threadIdx.x;
    const int tr = (tid >> 4) << 1;
    const int tc = (tid & 15) << 2;
    const int ar = tid >> 3, ak = (tid & 7) << 2;
    const int bk = tid >> 4, bc = (tid & 15) << 2;
    float acc[2][4] = {};
    for (int k0 = 0; k0 < C_DIM; k0 += 32) {
        float4 a4 = *reinterpret_cast<const float4*>(&x[(size_t)(row0 + ar) * C_DIM + k0 + ak]);
        float4 b4 = *reinterpret_cast<const float4*>(&W[(size_t)(k0 + bk) * HQK + wc0 + bc]);
        As[(ak + 0) * 68 + ar] = a4.x; As[(ak + 1) * 68 + ar] = a4.y;
        As[(ak + 2) * 68 + ar] = a4.z; As[(ak + 3) * 68 + ar] = a4.w;
        *reinterpret_cast<float4*>(&Bs[bk * 68 + bc]) = b4;
        __syncthreads();
#pragma unroll
        for (int kk = 0; kk < 32; ++kk) {
            float2 av = *reinterpret_cast<const float2*>(&As[kk * 68 + tr]);
            float4 bv = *reinterpret_cast<const float4*>(&Bs[kk * 68 + tc]);
            const float a[2] = {av.x, av.y};
            const float b[4] = {bv.x, bv.y, bv.z, bv.w};
#pragma unroll
            for (int i = 0; i < 2; ++i)
#pragma unroll
                for (int j = 0; j < 4; ++j) acc[i][j] = fmaf(a[i], b[j], acc[i][j]);
        }
        __syncthreads();
    }
    if (is_q) {
#pragma unroll
        for (int i = 0; i < 2; ++i) {
            float4 o = {acc[i][0], acc[i][1], acc[i][2], acc[i][3]};
            *reinterpret_cast<float4*>(&qbuf[(size_t)(row0 + tr + i) * HQK + col0 + tc]) = o;
        }
    } else {
#pragma unroll
        for (int j = 0; j < 4; ++j) {
            float2 o = {acc[0][j], acc[1][j]};
            *reinterpret_cast<float2*>(&kT[(size_t)(wc0 + tc + j) * T_CTX + row0 + tr]) = o;
        }
#pragma unroll
        for (int i = 0; i < 2; ++i) {
            float4 o = {acc[i][0], acc[i][1], acc[i][2], acc[i][3]};
            *reinterpret_cast<float4*>(&kbuf[(size_t)(row0 + tr + i) * HQK + wc0 + tc]) = o;
        }
    }
}

// ---------------------------------------------------------------------------
// Kernel 3 (tiny): fold kT columns by first-occurrence.  For each duplicate
// occurrence s' with f=first[s']: kT[d][f] += kT[d][s'] for all d.
// dup positions and first positions are disjoint sets -> no ordering hazard.
// ---------------------------------------------------------------------------
__global__ __launch_bounds__(256) void k_foldk(float* __restrict__ kT,
                                               const int* __restrict__ ndup_g,
                                               const int* __restrict__ dup_s,
                                               const int* __restrict__ dup_f) {
    const int nd = ndup_g[0];
    const int total = nd * HQK;
    for (int j = blockIdx.x * 256 + threadIdx.x; j < total; j += gridDim.x * 256) {
        const int e = j >> 8, d = j & 255;
        atomicAdd(&kT[(size_t)d * T_CTX + dup_f[e]], kT[(size_t)d * T_CTX + dup_s[e]]);
    }
}

// ---------------------------------------------------------------------------
// Kernel 4: fused scores+fold GEMM.  out_c[t][f] = q[t].kfold[f]/256 on the
// causal triangle (kfold = column-folded kT).  Epilogue subtracts the rare
// causal corrections: for dup s' (f=first[s']), rows f<=t<s' must not include
// k[s'] -> acc -= q[t].kbuf[s']  (UNSCALED -- final store applies the 1/256).
// ---------------------------------------------------------------------------
__global__ __launch_bounds__(512) void k_scores_gemm(const float* __restrict__ q,
                                                     const float* __restrict__ kT,
                                                     const float* __restrict__ kbuf,
                                                     const int* __restrict__ ndup_g,
                                                     const int* __restrict__ dup_s,
                                                     const int* __restrict__ dup_f,
                                                     float* __restrict__ out_c) {
    const int bt = blockIdx.x, bs = blockIdx.y;
    if (bs > bt) return;
    __shared__ __align__(16) float As[32 * 68];
    __shared__ __align__(16) float Bs[32 * 68];
    __shared__ int sds[2048];
    __shared__ int sdf[2048];
    __shared__ float skv[HQK];
    const int row0 = bt * 64;   // t
    const int col0 = bs * 64;   // f
    const int tid = threadIdx.x;
    const int nd = ndup_g[0];
    for (int i = tid; i < nd; i += 512) { sds[i] = dup_s[i]; sdf[i] = dup_f[i]; }
    const int tr = (tid >> 4) << 1;
    const int tc = (tid & 15) << 2;
    const int ar = tid >> 3, ak = (tid & 7) << 2;
    const int bk = tid >> 4, bc = (tid & 15) << 2;
    float acc[2][4] = {};
    for (int k0 = 0; k0 < HQK; k0 += 32) {
        float4 a4 = *reinterpret_cast<const float4*>(&q[(size_t)(row0 + ar) * HQK + k0 + ak]);
        float4 b4 = *reinterpret_cast<const float4*>(&kT[(size_t)(k0 + bk) * T_CTX + col0 + bc]);
        As[(ak + 0) * 68 + ar] = a4.x; As[(ak + 1) * 68 + ar] = a4.y;
        As[(ak + 2) * 68 + ar] = a4.z; As[(ak + 3) * 68 + ar] = a4.w;
        *reinterpret_cast<float4*>(&Bs[bk * 68 + bc]) = b4;
        __syncthreads();
#pragma unroll
        for (int kk = 0; kk < 32; ++kk) {
            float2 av = *reinterpret_cast<const float2*>(&As[kk * 68 + tr]);
            float4 bv = *reinterpret_cast<const float4*>(&Bs[kk * 68 + tc]);
            const float a[2] = {av.x, av.y};
            const float b[4] = {bv.x, bv.y, bv.z, bv.w};
#pragma unroll
            for (int i = 0; i < 2; ++i)
#pragma unroll
                for (int j = 0; j < 4; ++j) acc[i][j] = fmaf(a[i], b[j], acc[i][j]);
        }
        __syncthreads();
    }
    const float scale = 1.0f / 256.0f;
    // rare causal corrections (block-uniform branching)
    for (int e = 0; e < nd; ++e) {
        const int f = sdf[e], s2 = sds[e];
        const int tlo = (f > row0) ? f : row0;
        const int thi = (s2 - 1 < row0 + 63) ? (s2 - 1) : (row0 + 63);
        if (f < col0 || f >= col0 + 64 || tlo > thi) continue;
        __syncthreads();
        if (tid < 64) {
            float4 kv = *reinterpret_cast<const float4*>(&kbuf[(size_t)s2 * HQK + tid * 4]);
            *reinterpret_cast<float4*>(&skv[tid * 4]) = kv;
        }
        __syncthreads();
        const int jf = f - col0 - tc;
        if (jf >= 0 && jf < 4) {
#pragma unroll
            for (int i = 0; i < 2; ++i) {
                const int t = row0 + tr + i;
                if (t >= tlo && t <= thi) {
                    float dot = 0.0f;
                    const float4* qp = reinterpret_cast<const float4*>(&q[(size_t)t * HQK]);
#pragma unroll 8
                    for (int d4 = 0; d4 < 64; ++d4) {
                        float4 qv = qp[d4];
                        dot = fmaf(qv.x, skv[d4 * 4 + 0], fmaf(qv.y, skv[d4 * 4 + 1],
                              fmaf(qv.z, skv[d4 * 4 + 2], fmaf(qv.w, skv[d4 * 4 + 3], dot))));
                    }
                    // acc is UNSCALED; final store multiplies by scale, so
                    // subtract the raw dot (R9 bug: subtracted dot*scale).
#pragma unroll
                    for (int jj = 0; jj < 4; ++jj) if (jj == jf) acc[i][jj] -= dot;
                }
            }
        }
    }
#pragma unroll
    for (int i = 0; i < 2; ++i) {
        float4 o = {acc[i][0] * scale, acc[i][1] * scale, acc[i][2] * scale, acc[i][3] * scale};
        *reinterpret_cast<float4*>(&out_c[(size_t)(row0 + tr + i) * T_CTX + col0 + tc]) = o;
    }
}

// ---------------------------------------------------------------------------
// Kernel 5: pure expand.  out[t,v] = (m=vocab_map[v]) >= 0 && m <= t
//                                     ? out_c[t][m] : 0.
// Streaming aligned nontemporal float4 stores.
// ---------------------------------------------------------------------------
__global__ __launch_bounds__(256) void k_expand(const float* __restrict__ out_c,
                                                const int* __restrict__ vocab_map,
                                                float* __restrict__ out) {
    __shared__ float rowc[T_CTX];
    const int t = blockIdx.x;
    for (int i = threadIdx.x; i < T_CTX; i += 256) rowc[i] = out_c[(size_t)t * T_CTX + i];
    __syncthreads();
    float* __restrict__ orow = out + (size_t)t * NVOC;
    const int lead = (4 - (t & 3)) & 3;
    if ((int)threadIdx.x < lead) {
        int m = vocab_map[threadIdx.x];
        orow[threadIdx.x] = (m >= 0 && m <= t) ? rowc[m] : 0.0f;
    }
    const int nvec = (NVOC - lead) >> 2;
    for (int i = threadIdx.x; i < nvec; i += 256) {
        const int v = lead + (i << 2);
        int m0 = vocab_map[v + 0], m1 = vocab_map[v + 1];
        int m2 = vocab_map[v + 2], m3 = vocab_map[v + 3];
        nfloat4 o;
        o.x = (m0 >= 0 && m0 <= t) ? rowc[m0] : 0.0f;
        o.y = (m1 >= 0 && m1 <= t) ? rowc[m1] : 0.0f;
        o.z = (m2 >= 0 && m2 <= t) ? rowc[m2] : 0.0f;
        o.w = (m3 >= 0 && m3 <= t) ? rowc[m3] : 0.0f;
        __builtin_nontemporal_store(o, reinterpret_cast<nfloat4*>(&orow[v]));
    }
    for (int v = lead + (nvec << 2) + threadIdx.x; v < NVOC; v += 256) {
        int m = vocab_map[v];
        orow[v] = (m >= 0 && m <= t) ? rowc[m] : 0.0f;
    }
}

// ---------------------------------------------------------------------------
extern "C" void kernel_launch(void* const* d_in, const int* in_sizes, int n_in,
                              void* d_out, int out_size, void* d_ws, size_t ws_size,
                              hipStream_t stream) {
    const float* x   = (const float*)d_in[0];
    const int*   idx = (const int*)d_in[1];
    const float* Wq  = (const float*)d_in[2];
    const float* Wk  = (const float*)d_in[3];
    float* out = (float*)d_out;

    char* ws = (char*)d_ws;
    float* qbuf      = (float*)(ws);                               // 2 MB  [T][256]
    float* kT        = (float*)(ws + (2u << 20));                  // 2 MB  [256][T]
    float* kbuf      = (float*)(ws + (4u << 20));                  // 2 MB  [T][256]
    float* out_c     = (float*)(ws + (6u << 20));                  // 16 MB [T][T]
    int*   first     = (int*)(ws + (22u << 20));                   // 8 KB
    int*   vocab_map = (int*)(ws + (22u << 20) + (16u << 10));     // ~200 KB
    int*   ndup_g    = (int*)(ws + (23u << 20));                   // 4 B
    int*   dup_s     = (int*)(ws + (23u << 20) + 64);              // 8 KB
    int*   dup_f     = (int*)(ws + (23u << 20) + 64 + (8u << 10)); // 8 KB

    k_build_first<<<1, 1024, 0, stream>>>(idx, first, vocab_map, ndup_g, dup_s, dup_f);
    dim3 gg(32, 8);
    k_gemm_qk<<<gg, 512, 0, stream>>>(x, Wq, Wk, qbuf, kT, kbuf);
    k_foldk<<<64, 256, 0, stream>>>(kT, ndup_g, dup_s, dup_f);
    dim3 gs(32, 32);
    k_scores_gemm<<<gs, 512, 0, stream>>>(qbuf, kT, kbuf, ndup_g, dup_s, dup_f, out_c);
    k_expand<<<T_CTX, 256, 0, stream>>>(out_c, vocab_map, out);
}